// Round 8
// baseline (299.965 us; speedup 1.0000x reference)
//
#include <hip/hip_runtime.h>
#include <math.h>

#define SEQ 2048
#define EMB 2048
#define NHEAD 32
#define HDIM 64

typedef unsigned short u16;
typedef _Float16 half8 __attribute__((ext_vector_type(8)));
typedef _Float16 half4 __attribute__((ext_vector_type(4)));
typedef __attribute__((ext_vector_type(4))) float floatx4;

__device__ __forceinline__ floatx4 mfma_f16(half8 a, half8 b, floatx4 c) {
    return __builtin_amdgcn_mfma_f32_16x16x32_f16(a, b, c, 0, 0, 0);
}
__device__ __forceinline__ void load16(const u16* g, u16* l) {
    __builtin_amdgcn_global_load_lds(
        (const __attribute__((address_space(1))) unsigned int*)g,
        (__attribute__((address_space(3))) unsigned int*)l, 16, 0, 0);
}
__device__ __forceinline__ u16 h2u(_Float16 h) { return *reinterpret_cast<u16*>(&h); }

// =====================================================================
// fp32 -> fp16 converter, 4 tensors of 4M elements (blockIdx.y).
// =====================================================================
__global__ __launch_bounds__(256)
void cvt4(const float* __restrict__ X0, u16* __restrict__ Y0,
          const float* __restrict__ X1, u16* __restrict__ Y1,
          const float* __restrict__ X2, u16* __restrict__ Y2,
          const float* __restrict__ X3, u16* __restrict__ Y3)
{
    const float* Xs[4] = {X0, X1, X2, X3};
    u16* Ys[4] = {Y0, Y1, Y2, Y3};
    const float* X = Xs[blockIdx.y];
    u16* Y = Ys[blockIdx.y];
    const int i = (blockIdx.x * 256 + threadIdx.x) * 4;
    float4 v = *reinterpret_cast<const float4*>(X + i);
    half4 hv;
    hv.x = (_Float16)v.x; hv.y = (_Float16)v.y;
    hv.z = (_Float16)v.z; hv.w = (_Float16)v.w;
    *reinterpret_cast<half4*>(Y + i) = hv;
}

// =====================================================================
// 256x256 fp16 MFMA GEMM (NT), 8-wave (2Mx4N), BK=64, 8-phase counted-
// vmcnt pipeline, double-buffered 128 KiB LDS, mod-8 oct swizzle folded
// into the DMA fetch address (0 bank conflicts). r1 schedule (best
// measured across r1-r7). z = blockIdx.z:
// 0 -> F0 = acc + bk (fp32); 1 -> F1 = acc + bv (fp32);
// 2 -> Qb = fp16((acc + bq) * 0.125).
// =====================================================================
__global__ __launch_bounds__(512, 2)
void gemm256(const u16* __restrict__ A,
             const u16* __restrict__ B0, const u16* __restrict__ B1,
             const u16* __restrict__ B2,
             const float* __restrict__ bk, const float* __restrict__ bv,
             const float* __restrict__ bq,
             float* __restrict__ F0, float* __restrict__ F1,
             u16* __restrict__ Qb)
{
    __shared__ __align__(16) u16 As[2][256 * 64];
    __shared__ __align__(16) u16 Bs[2][256 * 64];

    const int tid = threadIdx.x;
    const int w = tid >> 6, lane = tid & 63;
    const int wm = w >> 2, wn = w & 3;          // 2 x 4 wave grid
    const int quad = lane >> 4, colk = lane & 15;
    const int lrow = lane >> 3, lphy = lane & 7;
    const int lsLog = (lphy - lrow) & 7;        // oct swizzle, pre-applied to src
    const int bn = blockIdx.x, bm = blockIdx.y, z = blockIdx.z;

    const u16* Bg  = (z == 0) ? B0 : (z == 1) ? B1 : B2;
    const u16* Ag  = A  + (size_t)(bm * 256 + lrow) * EMB + lsLog * 8;
    const u16* Bgp = Bg + (size_t)(bn * 256 + lrow) * EMB + lsLog * 8;

    const int kp0 = ((quad + colk) & 7) * 8;
    const int kp1 = ((quad + 4 + colk) & 7) * 8;
    int arow[8], brow[4];
    #pragma unroll
    for (int i = 0; i < 8; ++i) arow[i] = (wm * 128 + 16 * i + colk) * 64;
    #pragma unroll
    for (int j = 0; j < 4; ++j) brow[j] = (wn * 64 + 16 * j + colk) * 64;

    floatx4 acc[8][4];
    #pragma unroll
    for (int i = 0; i < 8; ++i)
        #pragma unroll
        for (int j = 0; j < 4; ++j) acc[i][j] = (floatx4){0.f, 0.f, 0.f, 0.f};

#define STAGE_A(MQ, BUF, KT) {                                                \
    _Pragma("unroll") for (int p_ = 0; p_ < 2; ++p_) {                        \
        const int r0_ = 128 * p_ + (MQ) * 64 + w * 8;                         \
        load16(Ag + (size_t)r0_ * EMB + (KT), &As[BUF][r0_ * 64 + lane * 8]); \
    } }
#define STAGE_B(NQ, BUF, KT) {                                                \
    _Pragma("unroll") for (int p_ = 0; p_ < 2; ++p_) {                        \
        const int b_ = w + 8 * p_;                                            \
        const int r0_ = 64 * (b_ >> 2) + (NQ) * 32 + (b_ & 3) * 8;            \
        load16(Bgp + (size_t)r0_ * EMB + (KT), &Bs[BUF][r0_ * 64 + lane * 8]);\
    } }

#define PHASE(MQ, NQ, BUF, STAGE, GUARD) {                                    \
    half8 af[4][2], bf[2][2];                                                 \
    _Pragma("unroll") for (int ii = 0; ii < 4; ++ii) {                        \
        const u16* ap_ = &As[BUF][arow[4 * (MQ) + ii]];                       \
        af[ii][0] = *reinterpret_cast<const half8*>(ap_ + kp0);               \
        af[ii][1] = *reinterpret_cast<const half8*>(ap_ + kp1);               \
    }                                                                         \
    _Pragma("unroll") for (int jj = 0; jj < 2; ++jj) {                        \
        const u16* bp_ = &Bs[BUF][brow[2 * (NQ) + jj]];                       \
        bf[jj][0] = *reinterpret_cast<const half8*>(bp_ + kp0);               \
        bf[jj][1] = *reinterpret_cast<const half8*>(bp_ + kp1);               \
    }                                                                         \
    STAGE                                                                     \
    __builtin_amdgcn_s_barrier();                                             \
    asm volatile("s_waitcnt lgkmcnt(0)" ::: "memory");                        \
    __builtin_amdgcn_s_setprio(1);                                            \
    _Pragma("unroll") for (int ii = 0; ii < 4; ++ii)                          \
        _Pragma("unroll") for (int jj = 0; jj < 2; ++jj) {                    \
            acc[4*(MQ)+ii][2*(NQ)+jj] =                                       \
                mfma_f16(af[ii][0], bf[jj][0], acc[4*(MQ)+ii][2*(NQ)+jj]);    \
            acc[4*(MQ)+ii][2*(NQ)+jj] =                                       \
                mfma_f16(af[ii][1], bf[jj][1], acc[4*(MQ)+ii][2*(NQ)+jj]);    \
        }                                                                     \
    __builtin_amdgcn_s_setprio(0);                                            \
    if (GUARD) asm volatile("s_waitcnt vmcnt(4)" ::: "memory");               \
    __builtin_amdgcn_s_barrier();                                             \
    __builtin_amdgcn_sched_barrier(0);                                        \
}

    // Prologue: K-tile 0 complete + first 2 chunks of K-tile 1.
    STAGE_B(0, 0, 0)
    STAGE_A(0, 0, 0)
    STAGE_A(1, 0, 0)
    STAGE_B(1, 0, 0)
    STAGE_B(0, 1, 64)
    STAGE_A(0, 1, 64)
    asm volatile("s_waitcnt vmcnt(4)" ::: "memory");
    __builtin_amdgcn_s_barrier();
    __builtin_amdgcn_sched_barrier(0);

    #pragma unroll 1
    for (int it = 0; it < 16; ++it) {
        const int k1 = ((2 * it + 1) & 31) * 64;
        const int k2 = ((2 * it + 2) & 31) * 64;
        const int k3 = ((2 * it + 3) & 31) * 64;
        PHASE(0, 0, 0, STAGE_A(1, 1, k1), 0)   // P1: buf1.A_mq1 <- 2i+1
        PHASE(1, 0, 0, STAGE_B(1, 1, k1), 0)   // P2: buf1.B_nq1 <- 2i+1
        PHASE(0, 1, 0, STAGE_B(0, 0, k2), 0)   // P3: buf0.B_nq0 <- 2i+2
        PHASE(1, 1, 0, STAGE_A(0, 0, k2), 1)   // P4: buf0.A_mq0, guard
        PHASE(0, 0, 1, STAGE_A(1, 0, k2), 0)   // P5: buf0.A_mq1 <- 2i+2
        PHASE(1, 0, 1, STAGE_B(1, 0, k2), 0)   // P6: buf0.B_nq1 <- 2i+2
        PHASE(0, 1, 1, STAGE_B(0, 1, k3), 0)   // P7: buf1.B_nq0 <- 2i+3
        PHASE(1, 1, 1, STAGE_A(0, 1, k3), 1)   // P8: buf1.A_mq0, guard
    }
    asm volatile("s_waitcnt vmcnt(0)" ::: "memory");  // drain before endpgm

#undef STAGE_A
#undef STAGE_B
#undef PHASE

    const float* bias = (z == 0) ? bk : (z == 1) ? bv : bq;
    #pragma unroll
    for (int i = 0; i < 8; ++i) {
        const int row = bm * 256 + wm * 128 + 16 * i + 4 * quad;
        #pragma unroll
        for (int j = 0; j < 4; ++j) {
            const int col = bn * 256 + wn * 64 + 16 * j + colk;
            const float bb = bias[col];
            #pragma unroll
            for (int r = 0; r < 4; ++r) {
                const size_t idx = (size_t)(row + r) * EMB + col;
                if (z == 2)
                    ((_Float16*)Qb)[idx] = (_Float16)((acc[i][j][r] + bb) * 0.125f);
                else
                    ((z == 0) ? F0 : F1)[idx] = acc[i][j][r] + bb;
            }
        }
    }
}

// =====================================================================
// 128x128 fp16 MFMA GEMM (NT), BK=64: kept for the O-projection
// (2048^2 output -> 256 blocks = full CU coverage).
// =====================================================================
__global__ __launch_bounds__(256)
void gemm16(const u16* __restrict__ A,
            const u16* __restrict__ B0, const u16* __restrict__ B1,
            const u16* __restrict__ B2,
            const float* __restrict__ bk, const float* __restrict__ bv,
            const float* __restrict__ bq,
            float* __restrict__ F0, float* __restrict__ F1,
            u16* __restrict__ Qb)
{
    __shared__ __align__(16) u16 As[128 * 64];
    __shared__ __align__(16) u16 Bs[128 * 64];

    const int tid = threadIdx.x;
    const int w = tid >> 6, lane = tid & 63;
    const int quad = lane >> 4, colk = lane & 15;
    const int bn = blockIdx.x, bm = blockIdx.y, z = blockIdx.z;
    const int wm = (w & 1) * 64, wn = (w >> 1) * 64;

    const u16* Bg = (z == 0) ? B0 : (z == 1) ? B1 : B2;

    const int srow = tid >> 3, sphy = tid & 7;
    const int sLog = (sphy - srow) & 7;
    size_t agof[4], bgof[4];
    int ldst[4];
    #pragma unroll
    for (int p = 0; p < 4; ++p) {
        const int row = srow + 32 * p;
        agof[p] = (size_t)(bm * 128 + row) * EMB + sLog * 8;
        bgof[p] = (size_t)(bn * 128 + row) * EMB + sLog * 8;
        ldst[p] = (tid + 256 * p) * 8;
    }

    const int aoct0 = ((quad + colk) & 7) * 8;
    const int aoct1 = ((quad + 4 + colk) & 7) * 8;

    floatx4 acc[4][4];
    #pragma unroll
    for (int i = 0; i < 4; ++i)
        #pragma unroll
        for (int j = 0; j < 4; ++j) acc[i][j] = (floatx4){0.f, 0.f, 0.f, 0.f};

    for (int kt = 0; kt < 2048; kt += 64) {
        __syncthreads();
        #pragma unroll
        for (int p = 0; p < 4; ++p) {
            load16(A  + agof[p] + kt, As + ldst[p]);
            load16(Bg + bgof[p] + kt, Bs + ldst[p]);
        }
        __syncthreads();

        half8 a0[4], a1[4], b0[4], b1[4];
        #pragma unroll
        for (int i = 0; i < 4; ++i) {
            a0[i] = *reinterpret_cast<const half8*>(&As[(wm + 16*i + colk) * 64 + aoct0]);
            a1[i] = *reinterpret_cast<const half8*>(&As[(wm + 16*i + colk) * 64 + aoct1]);
        }
        #pragma unroll
        for (int j = 0; j < 4; ++j) {
            b0[j] = *reinterpret_cast<const half8*>(&Bs[(wn + 16*j + colk) * 64 + aoct0]);
            b1[j] = *reinterpret_cast<const half8*>(&Bs[(wn + 16*j + colk) * 64 + aoct1]);
        }
        #pragma unroll
        for (int i = 0; i < 4; ++i)
            #pragma unroll
            for (int j = 0; j < 4; ++j) {
                acc[i][j] = mfma_f16(a0[i], b0[j], acc[i][j]);
                acc[i][j] = mfma_f16(a1[i], b1[j], acc[i][j]);
            }
    }

    const float* bias = (z == 0) ? bk : (z == 1) ? bv : bq;
    #pragma unroll
    for (int i = 0; i < 4; ++i) {
        const int row = bm * 128 + wm + 16*i + 4*quad;
        #pragma unroll
        for (int j = 0; j < 4; ++j) {
            const int col = bn * 128 + wn + 16*j + colk;
            const float bv2 = bias[col];
            #pragma unroll
            for (int r = 0; r < 4; ++r) {
                const size_t idx = (size_t)(row + r) * EMB + col;
                if (z == 2)
                    ((_Float16*)Qb)[idx] = (_Float16)((acc[i][j][r] + bv2) * 0.125f);
                else
                    ((z == 0) ? F0 : F1)[idx] = acc[i][j][r] + bv2;
            }
        }
    }
}

// =====================================================================
// QuotRem fake-quantize core (q_bits=1, r_bits=3, gs=16), exact ref
// semantics on fp32 pre-quant values.
// =====================================================================
__device__ __forceinline__ void quotrem16(float* x)
{
    float maxabs = 1e-8f, maxpos = -INFINITY, minval = INFINITY;
    #pragma unroll
    for (int i = 0; i < 16; ++i) {
        maxabs = fmaxf(maxabs, fabsf(x[i]));
        maxpos = fmaxf(maxpos, x[i]);
        minval = fminf(minval, x[i]);
    }
    const float lg = log2f(maxabs);
    const float bfl = exp2f(floorf(lg));
    const float bcl = exp2f(ceilf(lg));
    float base = (fabsf(maxabs - bfl) <= fabsf(bcl - maxabs)) ? bfl : bcl;
    base = fminf(fmaxf(base, 1.0f), 128.0f);
    const float sgn = (fabsf(maxpos) >= fabsf(minval)) ? 1.0f : -1.0f;
    const float hb = 0.5f * base, sb = sgn * base;

    float qs[16], r[16], maxr = 1e-8f;
    #pragma unroll
    for (int i = 0; i < 16; ++i) {
        qs[i] = (x[i] * sgn >= hb) ? sb : 0.0f;
        r[i]  = x[i] - qs[i];
        maxr  = fmaxf(maxr, fabsf(r[i]));
    }
    const float scale = maxr / 3.0f;
    #pragma unroll
    for (int i = 0; i < 16; ++i) {
        float rq = rintf(r[i] / scale);
        rq = fminf(fmaxf(rq, -4.0f), 3.0f);
        x[i] = qs[i] + rq * scale;
    }
}

// =====================================================================
// Merged dispatch: bid < 1024 -> K quant (same layout);
// 1024 <= bid < 1280 -> V quant + per-head transpose via LDS tile;
// bid >= 1280 -> Wo fp32 -> fp16 convert (into dead H16 region).
// =====================================================================
__global__ __launch_bounds__(256)
void quant_kv(const float* __restrict__ FK, u16* __restrict__ Kb,
              const float* __restrict__ FV, u16* __restrict__ Vt,
              const float* __restrict__ Wo, u16* __restrict__ Wo16)
{
    __shared__ u16 T[64 * 264];
    const int bid = blockIdx.x, t = threadIdx.x;

    if (bid >= 1280) {   // Wo convert: 4096 blocks x 1024 elements
        const int i = ((bid - 1280) * 256 + t) * 4;
        float4 v = *reinterpret_cast<const float4*>(Wo + i);
        half4 hv;
        hv.x = (_Float16)v.x; hv.y = (_Float16)v.y;
        hv.z = (_Float16)v.z; hv.w = (_Float16)v.w;
        *reinterpret_cast<half4*>(Wo16 + i) = hv;
        return;
    }

    if (bid < 1024) {    // K path
        const int g = bid * 256 + t;
        const float* p = FK + (size_t)g * 16;
        float x[16];
        #pragma unroll
        for (int i = 0; i < 16; i += 4)
            *reinterpret_cast<float4*>(&x[i]) = *reinterpret_cast<const float4*>(p + i);
        quotrem16(x);
        half8 h0, h1;
        #pragma unroll
        for (int i = 0; i < 8; ++i) {
            h0[i] = (_Float16)x[i];
            h1[i] = (_Float16)x[8 + i];
        }
        u16* o = Kb + (size_t)g * 16;
        *reinterpret_cast<half8*>(o) = h0;
        *reinterpret_cast<half8*>(o + 8) = h1;
        return;
    }

    const int l = bid - 1024;   // V path: 256 blocks
    const int sb = l >> 5, h = l & 31;
    const float* src = FV + (size_t)(sb * 256 + t) * EMB + h * HDIM;

    #pragma unroll
    for (int g4 = 0; g4 < 4; ++g4) {
        float x[16];
        #pragma unroll
        for (int i = 0; i < 16; i += 4)
            *reinterpret_cast<float4*>(&x[i]) =
                *reinterpret_cast<const float4*>(src + g4 * 16 + i);
        quotrem16(x);
        #pragma unroll
        for (int i = 0; i < 16; ++i)
            T[(g4 * 16 + i) * 264 + t] = h2u((_Float16)x[i]);
    }
    __syncthreads();

    const int d = t >> 2, seg = t & 3;
    u16* dst = Vt + (size_t)(h * HDIM + d) * SEQ + sb * 256 + seg * 64;
    #pragma unroll
    for (int jj = 0; jj < 8; ++jj)
        *reinterpret_cast<half8*>(dst + jj * 8) =
            *reinterpret_cast<const half8*>(&T[d * 264 + seg * 64 + jj * 8]);
}

// =====================================================================
// Causal flash attention, fp16 MFMA, S^T formulation, BC=128 windows,
// fixed-shift softmax (P = exp(s-4)). QBLK=128, 512 threads (8 waves),
// double-buffered K/V with counted vmcnt.
//
// r8 change: IN-REGISTER P (no Ps LDS buffer). The PV A-operand
// pa[seg] is a pure 4-lane permutation of the per-lane QK results:
// bytes 0-7 = half4 h[2seg+(quad>>1)] of lane 32*(quad&1)+colk;
// bytes 8-15 = same of lane +16 (derived from the old Ps index
// algebra -> identical fp16 bits in identical operand positions ->
// bit-identical output). Implemented as 8 __shfl + 4 selects per seg.
// Dropping Ps cuts LDS 98->64 KB => 2 blocks/CU (4 waves/SIMD), the
// latency-hiding this latency-bound kernel lacked (r7 analysis:
// ~85 us vs ~18 us LDS-pipe floor at 1 block/CU).
//
// Grid: 512 unpaired blocks, LPT-friendly qt permutation
// (qt = k<8 ? k : 23-k: dispatch round 1 ascending, backfill round
// descending -> early-finishing CUs pick up the largest remaining
// blocks under any work-conserving scheduler). XCD-clustered head
// decode unchanged (4 heads/XCD -> K+V 2 MB fits 4 MB L2).
// =====================================================================
__global__ __launch_bounds__(512, 4)
void flash128(const u16* __restrict__ Qb, const u16* __restrict__ Kb,
              const u16* __restrict__ Vt, u16* __restrict__ Ob)
{
    __shared__ __align__(16) u16 Ks[2][128 * 64];   // [key][d], swizzled octs
    __shared__ __align__(16) u16 Vs[2][64 * 128];   // [d][key], swizzled octs

    const int tid = threadIdx.x;
    const int w = tid >> 6, lane = tid & 63;
    const int wg = w >> 2, wl = w & 3;            // row-half group, wave-in-group
    const int quad = lane >> 4, colk = lane & 15;
    const int id = blockIdx.x;                    // 0..511
    const int h = (id & 7) * 4 + ((id >> 3) & 3); // head, XCD-clustered
    const int kk = id >> 5;                       // 0..15
    const int qt = (kk < 8) ? kk : (23 - kk);     // LPT permutation
    const int nw = qt + 1;

    int krow[2], koff[2], vd[2], voff[2], ldst[2];
    #pragma unroll
    for (int p = 0; p < 2; ++p) {
        const int c = tid + p * 512;
        krow[p] = c >> 3;
        koff[p] = (((c & 7) - krow[p]) & 7) * 8;
        vd[p]   = c >> 4;
        voff[p] = (((c & 15) - vd[p]) & 15) * 8;
        ldst[p] = c * 8;
    }
    const int kp0 = ((quad + colk) & 7) * 8;
    const int kp1 = ((quad + 4 + colk) & 7) * 8;
    const int rloc = wg * 64 + 16 * wl + colk;    // lane's q-row within block
    const int sl_lo = ((quad & 1) << 5) + colk;   // P-exchange source lanes
    const int sl_hi = sl_lo + 16;
    const bool hiT = (quad >> 1) != 0;

#define STAGEKV(KW, BUF) {                                                     \
    _Pragma("unroll") for (int p_ = 0; p_ < 2; ++p_) {                         \
        load16(Kb + (size_t)((KW) * 128 + krow[p_]) * EMB + h * HDIM + koff[p_],\
               &Ks[BUF][ldst[p_]]);                                            \
        load16(Vt + (size_t)(h * HDIM + vd[p_]) * SEQ + (KW) * 128 + voff[p_], \
               &Vs[BUF][ldst[p_]]);                                            \
    } }

    const int qrow_g = qt * 128 + rloc;

    const half8 qb0 = *reinterpret_cast<const half8*>(
        &Qb[(size_t)qrow_g * EMB + h * HDIM + quad * 8]);
    const half8 qb1 = *reinterpret_cast<const half8*>(
        &Qb[(size_t)qrow_g * EMB + h * HDIM + 32 + quad * 8]);

    STAGEKV(0, 0)                      // window 0 -> buf 0

    floatx4 o[4];
    #pragma unroll
    for (int t = 0; t < 4; ++t) o[t] = (floatx4){0.f, 0.f, 0.f, 0.f};
    float lsum = 0.f;
    int cur = 0;

    #pragma unroll 1
    for (int kw = 0; kw < nw; ++kw) {
        if (kw + 1 < nw) {
            STAGEKV(kw + 1, cur ^ 1)   // 4 loads in flight across compute
            asm volatile("s_waitcnt vmcnt(4)" ::: "memory");
        } else {
            asm volatile("s_waitcnt vmcnt(0)" ::: "memory");
        }
        __builtin_amdgcn_s_barrier();  // all waves' window-kw data landed
        __builtin_amdgcn_sched_barrier(0);

        floatx4 s[8];
        __builtin_amdgcn_s_setprio(1);
        #pragma unroll
        for (int t = 0; t < 8; ++t) {
            const half8 kb0 = *reinterpret_cast<const half8*>(&Ks[cur][(16*t + colk) * 64 + kp0]);
            const half8 kb1 = *reinterpret_cast<const half8*>(&Ks[cur][(16*t + colk) * 64 + kp1]);
            floatx4 zz = (floatx4){0.f, 0.f, 0.f, 0.f};
            zz = mfma_f16(kb0, qb0, zz);
            s[t] = mfma_f16(kb1, qb1, zz);
        }
        __builtin_amdgcn_s_setprio(0);
        if (kw == nw - 1) {
            #pragma unroll
            for (int t = 0; t < 8; ++t)
                #pragma unroll
                for (int r = 0; r < 4; ++r)
                    if (kw * 128 + 16*t + 4*quad + r > qrow_g) s[t][r] = -INFINITY;
        }

        half4 hfrag[8];                // P in registers (was Ps writes)
        #pragma unroll
        for (int t = 0; t < 8; ++t) {
            float pv0 = __expf(s[t][0] - 4.0f), pv1 = __expf(s[t][1] - 4.0f);
            float pv2 = __expf(s[t][2] - 4.0f), pv3 = __expf(s[t][3] - 4.0f);
            lsum += (pv0 + pv1) + (pv2 + pv3);
            half4 pw;
            pw.x = (_Float16)pv0; pw.y = (_Float16)pv1;
            pw.z = (_Float16)pv2; pw.w = (_Float16)pv3;
            hfrag[t] = pw;
        }

        // P exchange: pa[seg] lo-half4 from lane sl_lo's hfrag[2seg+hiT],
        // hi-half4 from lane sl_hi's. Same bits the Ps roundtrip moved.
        half8 pa[4];
        #pragma unroll
        for (int seg = 0; seg < 4; ++seg) {
            const uint2 ua = *reinterpret_cast<const uint2*>(&hfrag[2*seg]);
            const uint2 ub = *reinterpret_cast<const uint2*>(&hfrag[2*seg+1]);
            const unsigned a0 = __shfl(ua.x, sl_lo), a1 = __shfl(ua.y, sl_lo);
            const unsigned b0 = __shfl(ub.x, sl_lo), b1 = __shfl(ub.y, sl_lo);
            const unsigned c0 = __shfl(ua.x, sl_hi), c1 = __shfl(ua.y, sl_hi);
            const unsigned d0 = __shfl(ub.x, sl_hi), d1 = __shfl(ub.y, sl_hi);
            uint4 wv;
            wv.x = hiT ? b0 : a0; wv.y = hiT ? b1 : a1;
            wv.z = hiT ? d0 : c0; wv.w = hiT ? d1 : c1;
            pa[seg] = *reinterpret_cast<const half8*>(&wv);
        }

        __builtin_amdgcn_s_setprio(1);
        #pragma unroll
        for (int t = 0; t < 4; ++t) {
            #pragma unroll
            for (int seg = 0; seg < 4; ++seg) {
                const int vp = ((4*seg + quad + colk) & 15) * 8;
                const half8 vb = *reinterpret_cast<const half8*>(&Vs[cur][(16*t + colk) * 128 + vp]);
                o[t] = mfma_f16(pa[seg], vb, o[t]);
            }
        }
        __builtin_amdgcn_s_setprio(0);

        __builtin_amdgcn_s_barrier();  // all waves done with bufs[cur]
        __builtin_amdgcn_sched_barrier(0);
        cur ^= 1;
    }

    lsum += __shfl_xor(lsum, 16, 64);
    lsum += __shfl_xor(lsum, 32, 64);

    float invr[4];
    #pragma unroll
    for (int r = 0; r < 4; ++r) invr[r] = 1.0f / __shfl(lsum, 4*quad + r, 64);
    #pragma unroll
    for (int t = 0; t < 4; ++t)
        #pragma unroll
        for (int r = 0; r < 4; ++r) {
            const int row = qt * 128 + wg * 64 + 16*wl + 4*quad + r;
            ((_Float16*)Ob)[(size_t)row * EMB + h * HDIM + 16*t + colk] =
                (_Float16)(o[t][r] * invr[r]);
        }
#undef STAGEKV
}

// =====================================================================
// Orchestration (5 dispatches). Workspace (64 MB) + d_out scratch:
//  ws: H16[0,8) Wk16[8,16) Wv16[16,24) FK[24,40) FV[40,56) Qbuf[56,64)
//  d_out: Wq16[0,8) — dead after dispatch 2
//  dispatch 3 (quant_kv): Kbuf[8,16) (Wk16 dead), Vt[16,24) (Wv16 dead),
//                         Wo16[0,8) (H16 dead)
//  dispatch 4 (flash):    Obuf[24,32) (FK dead)
//  dispatch 5 (gemm O):   reads Obuf + Wo16, writes out (Wq16 dead)
// =====================================================================
extern "C" void kernel_launch(void* const* d_in, const int* in_sizes, int n_in,
                              void* d_out, int out_size, void* d_ws, size_t ws_size,
                              hipStream_t stream)
{
    const float* hidden = (const float*)d_in[0];
    const float* Wq = (const float*)d_in[1];
    const float* bq = (const float*)d_in[2];
    const float* Wk = (const float*)d_in[3];
    const float* bk = (const float*)d_in[4];
    const float* Wv = (const float*)d_in[5];
    const float* bv = (const float*)d_in[6];
    const float* Wo = (const float*)d_in[7];
    const float* bo = (const float*)d_in[8];
    float* out = (float*)d_out;

    char* ws = (char*)d_ws;
    const size_t MB = 1024 * 1024;
    u16*   H16  = (u16*)(ws);
    u16*   Wk16 = (u16*)(ws + 8 * MB);
    u16*   Wv16 = (u16*)(ws + 16 * MB);
    float* FK   = (float*)(ws + 24 * MB);
    float* FV   = (float*)(ws + 40 * MB);
    u16*   Qbuf = (u16*)(ws + 56 * MB);
    u16*   Kbuf = (u16*)(ws + 8 * MB);
    u16*   Vtb  = (u16*)(ws + 16 * MB);
    u16*   Wo16 = (u16*)(ws);            // over dead H16 (after dispatch 2)
    u16*   Obuf = (u16*)(ws + 24 * MB);  // over dead FK (after dispatch 3)
    u16*   Wq16 = (u16*)d_out;           // d_out scratch, dead after disp 2

    const dim3 cb(256);
    float* nilf = nullptr; u16* nil16 = nullptr;

    // 1. hidden/Wk/Wv/Wq -> fp16
    hipLaunchKernelGGL(cvt4, dim3(4096, 4), cb, 0, stream,
                       hidden, H16, Wk, Wk16, Wv, Wv16, Wq, Wq16);
    // 2. K/V/Q projections, 256^2 8-phase pipelined GEMM (r1 schedule)
    hipLaunchKernelGGL(gemm256, dim3(8, 8, 3), dim3(512), 0, stream,
                       H16, Wk16, Wv16, Wq16, bk, bv, bq, FK, FV, Qbuf);
    // 3. quantize K + V (V transposed) + Wo convert (merged)
    hipLaunchKernelGGL(quant_kv, dim3(1280 + 4096), cb, 0, stream,
                       FK, Kbuf, FV, Vtb, Wo, Wo16);
    // 4. attention: 512 blocks, in-register P, 2 blocks/CU
    hipLaunchKernelGGL(flash128, dim3(512), dim3(512), 0, stream,
                       Qbuf, Kbuf, Vtb, Obuf);
    // 5. O projection, full-K single dispatch: out = Obuf @ Wo^T + bo
    hipLaunchKernelGGL(gemm16, dim3(16, 16, 1), cb, 0, stream,
                       Obuf, Wo16, nil16, nil16, bo, nilf, nilf,
                       out, nilf, nil16);
}

// Round 9
// 292.205 us; speedup vs baseline: 1.0266x; 1.0266x over previous
//
#include <hip/hip_runtime.h>
#include <math.h>

#define SEQ 2048
#define EMB 2048
#define NHEAD 32
#define HDIM 64

typedef unsigned short u16;
typedef _Float16 half8 __attribute__((ext_vector_type(8)));
typedef _Float16 half4 __attribute__((ext_vector_type(4)));
typedef __attribute__((ext_vector_type(4))) float floatx4;

__device__ __forceinline__ floatx4 mfma_f16(half8 a, half8 b, floatx4 c) {
    return __builtin_amdgcn_mfma_f32_16x16x32_f16(a, b, c, 0, 0, 0);
}
__device__ __forceinline__ void load16(const u16* g, u16* l) {
    __builtin_amdgcn_global_load_lds(
        (const __attribute__((address_space(1))) unsigned int*)g,
        (__attribute__((address_space(3))) unsigned int*)l, 16, 0, 0);
}
__device__ __forceinline__ u16 h2u(_Float16 h) { return *reinterpret_cast<u16*>(&h); }

// =====================================================================
// fp32 -> fp16 converter, 4 tensors of 4M elements (blockIdx.y).
// =====================================================================
__global__ __launch_bounds__(256)
void cvt4(const float* __restrict__ X0, u16* __restrict__ Y0,
          const float* __restrict__ X1, u16* __restrict__ Y1,
          const float* __restrict__ X2, u16* __restrict__ Y2,
          const float* __restrict__ X3, u16* __restrict__ Y3)
{
    const float* Xs[4] = {X0, X1, X2, X3};
    u16* Ys[4] = {Y0, Y1, Y2, Y3};
    const float* X = Xs[blockIdx.y];
    u16* Y = Ys[blockIdx.y];
    const int i = (blockIdx.x * 256 + threadIdx.x) * 4;
    float4 v = *reinterpret_cast<const float4*>(X + i);
    half4 hv;
    hv.x = (_Float16)v.x; hv.y = (_Float16)v.y;
    hv.z = (_Float16)v.z; hv.w = (_Float16)v.w;
    *reinterpret_cast<half4*>(Y + i) = hv;
}

// =====================================================================
// 256x256 fp16 MFMA GEMM (NT), 8-wave (2Mx4N), BK=64, 8-phase counted-
// vmcnt pipeline, double-buffered 128 KiB LDS, mod-8 oct swizzle folded
// into the DMA fetch address (0 bank conflicts). r1 schedule (best
// measured across r1-r8). z = blockIdx.z:
// 0 -> F0 = acc + bk (fp32); 1 -> F1 = acc + bv (fp32);
// 2 -> Qb = fp16((acc + bq) * 0.125);
// 3 -> Wo fp32 -> fp16 on the 64 otherwise-idle CUs (pure streaming,
//      no LDS; r9: moved out of quant_kv to overlap with the GEMM).
// =====================================================================
__global__ __launch_bounds__(512, 2)
void gemm256(const u16* __restrict__ A,
             const u16* __restrict__ B0, const u16* __restrict__ B1,
             const u16* __restrict__ B2,
             const float* __restrict__ bk, const float* __restrict__ bv,
             const float* __restrict__ bq,
             const float* __restrict__ Wo, u16* __restrict__ Wo16,
             float* __restrict__ F0, float* __restrict__ F1,
             u16* __restrict__ Qb)
{
    __shared__ __align__(16) u16 As[2][256 * 64];
    __shared__ __align__(16) u16 Bs[2][256 * 64];

    const int tid = threadIdx.x;
    const int bn = blockIdx.x, bm = blockIdx.y, z = blockIdx.z;

    if (z == 3) {        // Wo convert: 64 blocks x 512 threads x 128 elems
        const int b = bm * 8 + bn;
        #pragma unroll
        for (int c = 0; c < 32; ++c) {
            const int i = ((c * 64 + b) * 512 + tid) * 4;
            float4 v = *reinterpret_cast<const float4*>(Wo + i);
            half4 hv;
            hv.x = (_Float16)v.x; hv.y = (_Float16)v.y;
            hv.z = (_Float16)v.z; hv.w = (_Float16)v.w;
            *reinterpret_cast<half4*>(Wo16 + i) = hv;
        }
        return;
    }

    const int w = tid >> 6, lane = tid & 63;
    const int wm = w >> 2, wn = w & 3;          // 2 x 4 wave grid
    const int quad = lane >> 4, colk = lane & 15;
    const int lrow = lane >> 3, lphy = lane & 7;
    const int lsLog = (lphy - lrow) & 7;        // oct swizzle, pre-applied to src

    const u16* Bg  = (z == 0) ? B0 : (z == 1) ? B1 : B2;
    const u16* Ag  = A  + (size_t)(bm * 256 + lrow) * EMB + lsLog * 8;
    const u16* Bgp = Bg + (size_t)(bn * 256 + lrow) * EMB + lsLog * 8;

    const int kp0 = ((quad + colk) & 7) * 8;
    const int kp1 = ((quad + 4 + colk) & 7) * 8;
    int arow[8], brow[4];
    #pragma unroll
    for (int i = 0; i < 8; ++i) arow[i] = (wm * 128 + 16 * i + colk) * 64;
    #pragma unroll
    for (int j = 0; j < 4; ++j) brow[j] = (wn * 64 + 16 * j + colk) * 64;

    floatx4 acc[8][4];
    #pragma unroll
    for (int i = 0; i < 8; ++i)
        #pragma unroll
        for (int j = 0; j < 4; ++j) acc[i][j] = (floatx4){0.f, 0.f, 0.f, 0.f};

#define STAGE_A(MQ, BUF, KT) {                                                \
    _Pragma("unroll") for (int p_ = 0; p_ < 2; ++p_) {                        \
        const int r0_ = 128 * p_ + (MQ) * 64 + w * 8;                         \
        load16(Ag + (size_t)r0_ * EMB + (KT), &As[BUF][r0_ * 64 + lane * 8]); \
    } }
#define STAGE_B(NQ, BUF, KT) {                                                \
    _Pragma("unroll") for (int p_ = 0; p_ < 2; ++p_) {                        \
        const int b_ = w + 8 * p_;                                            \
        const int r0_ = 64 * (b_ >> 2) + (NQ) * 32 + (b_ & 3) * 8;            \
        load16(Bgp + (size_t)r0_ * EMB + (KT), &Bs[BUF][r0_ * 64 + lane * 8]);\
    } }

#define PHASE(MQ, NQ, BUF, STAGE, GUARD) {                                    \
    half8 af[4][2], bf[2][2];                                                 \
    _Pragma("unroll") for (int ii = 0; ii < 4; ++ii) {                        \
        const u16* ap_ = &As[BUF][arow[4 * (MQ) + ii]];                       \
        af[ii][0] = *reinterpret_cast<const half8*>(ap_ + kp0);               \
        af[ii][1] = *reinterpret_cast<const half8*>(ap_ + kp1);               \
    }                                                                         \
    _Pragma("unroll") for (int jj = 0; jj < 2; ++jj) {                        \
        const u16* bp_ = &Bs[BUF][brow[2 * (NQ) + jj]];                       \
        bf[jj][0] = *reinterpret_cast<const half8*>(bp_ + kp0);               \
        bf[jj][1] = *reinterpret_cast<const half8*>(bp_ + kp1);               \
    }                                                                         \
    STAGE                                                                     \
    __builtin_amdgcn_s_barrier();                                             \
    asm volatile("s_waitcnt lgkmcnt(0)" ::: "memory");                        \
    __builtin_amdgcn_s_setprio(1);                                            \
    _Pragma("unroll") for (int ii = 0; ii < 4; ++ii)                          \
        _Pragma("unroll") for (int jj = 0; jj < 2; ++jj) {                    \
            acc[4*(MQ)+ii][2*(NQ)+jj] =                                       \
                mfma_f16(af[ii][0], bf[jj][0], acc[4*(MQ)+ii][2*(NQ)+jj]);    \
            acc[4*(MQ)+ii][2*(NQ)+jj] =                                       \
                mfma_f16(af[ii][1], bf[jj][1], acc[4*(MQ)+ii][2*(NQ)+jj]);    \
        }                                                                     \
    __builtin_amdgcn_s_setprio(0);                                            \
    if (GUARD) asm volatile("s_waitcnt vmcnt(4)" ::: "memory");               \
    __builtin_amdgcn_s_barrier();                                             \
    __builtin_amdgcn_sched_barrier(0);                                        \
}

    // Prologue: K-tile 0 complete + first 2 chunks of K-tile 1.
    STAGE_B(0, 0, 0)
    STAGE_A(0, 0, 0)
    STAGE_A(1, 0, 0)
    STAGE_B(1, 0, 0)
    STAGE_B(0, 1, 64)
    STAGE_A(0, 1, 64)
    asm volatile("s_waitcnt vmcnt(4)" ::: "memory");
    __builtin_amdgcn_s_barrier();
    __builtin_amdgcn_sched_barrier(0);

    #pragma unroll 1
    for (int it = 0; it < 16; ++it) {
        const int k1 = ((2 * it + 1) & 31) * 64;
        const int k2 = ((2 * it + 2) & 31) * 64;
        const int k3 = ((2 * it + 3) & 31) * 64;
        PHASE(0, 0, 0, STAGE_A(1, 1, k1), 0)   // P1: buf1.A_mq1 <- 2i+1
        PHASE(1, 0, 0, STAGE_B(1, 1, k1), 0)   // P2: buf1.B_nq1 <- 2i+1
        PHASE(0, 1, 0, STAGE_B(0, 0, k2), 0)   // P3: buf0.B_nq0 <- 2i+2
        PHASE(1, 1, 0, STAGE_A(0, 0, k2), 1)   // P4: buf0.A_mq0, guard
        PHASE(0, 0, 1, STAGE_A(1, 0, k2), 0)   // P5: buf0.A_mq1 <- 2i+2
        PHASE(1, 0, 1, STAGE_B(1, 0, k2), 0)   // P6: buf0.B_nq1 <- 2i+2
        PHASE(0, 1, 1, STAGE_B(0, 1, k3), 0)   // P7: buf1.B_nq0 <- 2i+3
        PHASE(1, 1, 1, STAGE_A(0, 1, k3), 1)   // P8: buf1.A_mq0, guard
    }
    asm volatile("s_waitcnt vmcnt(0)" ::: "memory");  // drain before endpgm

#undef STAGE_A
#undef STAGE_B
#undef PHASE

    const float* bias = (z == 0) ? bk : (z == 1) ? bv : bq;
    #pragma unroll
    for (int i = 0; i < 8; ++i) {
        const int row = bm * 256 + wm * 128 + 16 * i + 4 * quad;
        #pragma unroll
        for (int j = 0; j < 4; ++j) {
            const int col = bn * 256 + wn * 64 + 16 * j + colk;
            const float bb = bias[col];
            #pragma unroll
            for (int r = 0; r < 4; ++r) {
                const size_t idx = (size_t)(row + r) * EMB + col;
                if (z == 2)
                    ((_Float16*)Qb)[idx] = (_Float16)((acc[i][j][r] + bb) * 0.125f);
                else
                    ((z == 0) ? F0 : F1)[idx] = acc[i][j][r] + bb;
            }
        }
    }
}

// =====================================================================
// 128x128 fp16 MFMA GEMM (NT), BK=64: kept for the O-projection
// (2048^2 output -> 256 blocks = full CU coverage; measured at its
// LDS-read-BW roof ~30 us).
// =====================================================================
__global__ __launch_bounds__(256)
void gemm16(const u16* __restrict__ A,
            const u16* __restrict__ B0, const u16* __restrict__ B1,
            const u16* __restrict__ B2,
            const float* __restrict__ bk, const float* __restrict__ bv,
            const float* __restrict__ bq,
            float* __restrict__ F0, float* __restrict__ F1,
            u16* __restrict__ Qb)
{
    __shared__ __align__(16) u16 As[128 * 64];
    __shared__ __align__(16) u16 Bs[128 * 64];

    const int tid = threadIdx.x;
    const int w = tid >> 6, lane = tid & 63;
    const int quad = lane >> 4, colk = lane & 15;
    const int bn = blockIdx.x, bm = blockIdx.y, z = blockIdx.z;
    const int wm = (w & 1) * 64, wn = (w >> 1) * 64;

    const u16* Bg = (z == 0) ? B0 : (z == 1) ? B1 : B2;

    const int srow = tid >> 3, sphy = tid & 7;
    const int sLog = (sphy - srow) & 7;
    size_t agof[4], bgof[4];
    int ldst[4];
    #pragma unroll
    for (int p = 0; p < 4; ++p) {
        const int row = srow + 32 * p;
        agof[p] = (size_t)(bm * 128 + row) * EMB + sLog * 8;
        bgof[p] = (size_t)(bn * 128 + row) * EMB + sLog * 8;
        ldst[p] = (tid + 256 * p) * 8;
    }

    const int aoct0 = ((quad + colk) & 7) * 8;
    const int aoct1 = ((quad + 4 + colk) & 7) * 8;

    floatx4 acc[4][4];
    #pragma unroll
    for (int i = 0; i < 4; ++i)
        #pragma unroll
        for (int j = 0; j < 4; ++j) acc[i][j] = (floatx4){0.f, 0.f, 0.f, 0.f};

    for (int kt = 0; kt < 2048; kt += 64) {
        __syncthreads();
        #pragma unroll
        for (int p = 0; p < 4; ++p) {
            load16(A  + agof[p] + kt, As + ldst[p]);
            load16(Bg + bgof[p] + kt, Bs + ldst[p]);
        }
        __syncthreads();

        half8 a0[4], a1[4], b0[4], b1[4];
        #pragma unroll
        for (int i = 0; i < 4; ++i) {
            a0[i] = *reinterpret_cast<const half8*>(&As[(wm + 16*i + colk) * 64 + aoct0]);
            a1[i] = *reinterpret_cast<const half8*>(&As[(wm + 16*i + colk) * 64 + aoct1]);
        }
        #pragma unroll
        for (int j = 0; j < 4; ++j) {
            b0[j] = *reinterpret_cast<const half8*>(&Bs[(wn + 16*j + colk) * 64 + aoct0]);
            b1[j] = *reinterpret_cast<const half8*>(&Bs[(wn + 16*j + colk) * 64 + aoct1]);
        }
        #pragma unroll
        for (int i = 0; i < 4; ++i)
            #pragma unroll
            for (int j = 0; j < 4; ++j) {
                acc[i][j] = mfma_f16(a0[i], b0[j], acc[i][j]);
                acc[i][j] = mfma_f16(a1[i], b1[j], acc[i][j]);
            }
    }

    const float* bias = (z == 0) ? bk : (z == 1) ? bv : bq;
    #pragma unroll
    for (int i = 0; i < 4; ++i) {
        const int row = bm * 128 + wm + 16*i + 4*quad;
        #pragma unroll
        for (int j = 0; j < 4; ++j) {
            const int col = bn * 128 + wn + 16*j + colk;
            const float bv2 = bias[col];
            #pragma unroll
            for (int r = 0; r < 4; ++r) {
                const size_t idx = (size_t)(row + r) * EMB + col;
                if (z == 2)
                    ((_Float16*)Qb)[idx] = (_Float16)((acc[i][j][r] + bv2) * 0.125f);
                else
                    ((z == 0) ? F0 : F1)[idx] = acc[i][j][r] + bv2;
            }
        }
    }
}

// =====================================================================
// QuotRem fake-quantize core (q_bits=1, r_bits=3, gs=16), exact ref
// semantics on fp32 pre-quant values.
// =====================================================================
__device__ __forceinline__ void quotrem16(float* x)
{
    float maxabs = 1e-8f, maxpos = -INFINITY, minval = INFINITY;
    #pragma unroll
    for (int i = 0; i < 16; ++i) {
        maxabs = fmaxf(maxabs, fabsf(x[i]));
        maxpos = fmaxf(maxpos, x[i]);
        minval = fminf(minval, x[i]);
    }
    const float lg = log2f(maxabs);
    const float bfl = exp2f(floorf(lg));
    const float bcl = exp2f(ceilf(lg));
    float base = (fabsf(maxabs - bfl) <= fabsf(bcl - maxabs)) ? bfl : bcl;
    base = fminf(fmaxf(base, 1.0f), 128.0f);
    const float sgn = (fabsf(maxpos) >= fabsf(minval)) ? 1.0f : -1.0f;
    const float hb = 0.5f * base, sb = sgn * base;

    float qs[16], r[16], maxr = 1e-8f;
    #pragma unroll
    for (int i = 0; i < 16; ++i) {
        qs[i] = (x[i] * sgn >= hb) ? sb : 0.0f;
        r[i]  = x[i] - qs[i];
        maxr  = fmaxf(maxr, fabsf(r[i]));
    }
    const float scale = maxr / 3.0f;
    #pragma unroll
    for (int i = 0; i < 16; ++i) {
        float rq = rintf(r[i] / scale);
        rq = fminf(fmaxf(rq, -4.0f), 3.0f);
        x[i] = qs[i] + rq * scale;
    }
}

// =====================================================================
// quant_kv (r9: Wo-convert branch moved to gemm256 z=3):
// bid < 1024 -> K quant (same layout, packed half8 stores);
// bid >= 1024 -> V quant + per-head transpose via LDS tile.
// =====================================================================
__global__ __launch_bounds__(256)
void quant_kv(const float* __restrict__ FK, u16* __restrict__ Kb,
              const float* __restrict__ FV, u16* __restrict__ Vt)
{
    __shared__ u16 T[64 * 264];
    const int bid = blockIdx.x, t = threadIdx.x;

    if (bid < 1024) {    // K path
        const int g = bid * 256 + t;
        const float* p = FK + (size_t)g * 16;
        float x[16];
        #pragma unroll
        for (int i = 0; i < 16; i += 4)
            *reinterpret_cast<float4*>(&x[i]) = *reinterpret_cast<const float4*>(p + i);
        quotrem16(x);
        half8 h0, h1;
        #pragma unroll
        for (int i = 0; i < 8; ++i) {
            h0[i] = (_Float16)x[i];
            h1[i] = (_Float16)x[8 + i];
        }
        u16* o = Kb + (size_t)g * 16;
        *reinterpret_cast<half8*>(o) = h0;
        *reinterpret_cast<half8*>(o + 8) = h1;
        return;
    }

    const int l = bid - 1024;   // V path: 256 blocks
    const int sb = l >> 5, h = l & 31;
    const float* src = FV + (size_t)(sb * 256 + t) * EMB + h * HDIM;

    #pragma unroll
    for (int g4 = 0; g4 < 4; ++g4) {
        float x[16];
        #pragma unroll
        for (int i = 0; i < 16; i += 4)
            *reinterpret_cast<float4*>(&x[i]) =
                *reinterpret_cast<const float4*>(src + g4 * 16 + i);
        quotrem16(x);
        #pragma unroll
        for (int i = 0; i < 16; ++i)
            T[(g4 * 16 + i) * 264 + t] = h2u((_Float16)x[i]);
    }
    __syncthreads();

    const int d = t >> 2, seg = t & 3;
    u16* dst = Vt + (size_t)(h * HDIM + d) * SEQ + sb * 256 + seg * 64;
    #pragma unroll
    for (int jj = 0; jj < 8; ++jj)
        *reinterpret_cast<half8*>(dst + jj * 8) =
            *reinterpret_cast<const half8*>(&T[d * 264 + seg * 64 + jj * 8]);
}

// =====================================================================
// Causal flash attention, fp16 MFMA, S^T formulation, BC=128 windows,
// fixed-shift softmax (P = exp(s-4)). QBLK=128, 512 threads (8 waves),
// double-buffered K/V with counted vmcnt, setprio around MFMA clusters
// (r7 configuration — best measured total). Grid: 256 paired blocks
// (uniform 17 windows), XCD-clustered.
// =====================================================================
__global__ __launch_bounds__(512)
void flash128(const u16* __restrict__ Qb, const u16* __restrict__ Kb,
              const u16* __restrict__ Vt, u16* __restrict__ Ob)
{
    __shared__ __align__(16) u16 Ks[2][128 * 64];   // [key][d], swizzled octs
    __shared__ __align__(16) u16 Vs[2][64 * 128];   // [d][key], swizzled octs
    __shared__ __align__(16) u16 Ps[128 * 136];     // P[q][key], wave-local rows

    const int tid = threadIdx.x;
    const int w = tid >> 6, lane = tid & 63;
    const int wg = w >> 2, wl = w & 3;            // row-half group, wave-in-group
    const int quad = lane >> 4, colk = lane & 15;
    const int id = blockIdx.x;                    // 0..255
    const int h = (id & 7) * 4 + ((id >> 3) & 3); // head, XCD-clustered
    const int pairb = id >> 5;                    // 0..7

    int krow[2], koff[2], vd[2], voff[2], ldst[2];
    #pragma unroll
    for (int p = 0; p < 2; ++p) {
        const int c = tid + p * 512;
        krow[p] = c >> 3;
        koff[p] = (((c & 7) - krow[p]) & 7) * 8;
        vd[p]   = c >> 4;
        voff[p] = (((c & 15) - vd[p]) & 15) * 8;
        ldst[p] = c * 8;
    }
    const int kp0 = ((quad + colk) & 7) * 8;
    const int kp1 = ((quad + 4 + colk) & 7) * 8;
    const int rloc = wg * 64 + 16 * wl + colk;    // lane's q-row within block

#define STAGEKV(KW, BUF) {                                                     \
    _Pragma("unroll") for (int p_ = 0; p_ < 2; ++p_) {                         \
        load16(Kb + (size_t)((KW) * 128 + krow[p_]) * EMB + h * HDIM + koff[p_],\
               &Ks[BUF][ldst[p_]]);                                            \
        load16(Vt + (size_t)(h * HDIM + vd[p_]) * SEQ + (KW) * 128 + voff[p_], \
               &Vs[BUF][ldst[p_]]);                                            \
    } }

    #pragma unroll
    for (int pass = 0; pass < 2; ++pass) {
        const int qt = pass ? (15 - pairb) : pairb;
        const int nw = qt + 1;
        const int qrow_g = qt * 128 + rloc;

        const half8 qb0 = *reinterpret_cast<const half8*>(
            &Qb[(size_t)qrow_g * EMB + h * HDIM + quad * 8]);
        const half8 qb1 = *reinterpret_cast<const half8*>(
            &Qb[(size_t)qrow_g * EMB + h * HDIM + 32 + quad * 8]);

        STAGEKV(0, 0)                      // window 0 -> buf 0

        floatx4 o[4];
        #pragma unroll
        for (int t = 0; t < 4; ++t) o[t] = (floatx4){0.f, 0.f, 0.f, 0.f};
        float lsum = 0.f;
        int cur = 0;

        #pragma unroll 1
        for (int kw = 0; kw < nw; ++kw) {
            if (kw + 1 < nw) {
                STAGEKV(kw + 1, cur ^ 1)   // 4 loads in flight across compute
                asm volatile("s_waitcnt vmcnt(4)" ::: "memory");
            } else {
                asm volatile("s_waitcnt vmcnt(0)" ::: "memory");
            }
            __builtin_amdgcn_s_barrier();  // all waves' window-kw data landed
            __builtin_amdgcn_sched_barrier(0);

            floatx4 s[8];
            __builtin_amdgcn_s_setprio(1);
            #pragma unroll
            for (int t = 0; t < 8; ++t) {
                const half8 kb0 = *reinterpret_cast<const half8*>(&Ks[cur][(16*t + colk) * 64 + kp0]);
                const half8 kb1 = *reinterpret_cast<const half8*>(&Ks[cur][(16*t + colk) * 64 + kp1]);
                floatx4 zz = (floatx4){0.f, 0.f, 0.f, 0.f};
                zz = mfma_f16(kb0, qb0, zz);
                s[t] = mfma_f16(kb1, qb1, zz);
            }
            __builtin_amdgcn_s_setprio(0);
            if (kw == nw - 1) {
                #pragma unroll
                for (int t = 0; t < 8; ++t)
                    #pragma unroll
                    for (int r = 0; r < 4; ++r)
                        if (kw * 128 + 16*t + 4*quad + r > qrow_g) s[t][r] = -INFINITY;
            }

            #pragma unroll
            for (int t = 0; t < 8; ++t) {
                half4 pw;
                float pv0 = __expf(s[t][0] - 4.0f), pv1 = __expf(s[t][1] - 4.0f);
                float pv2 = __expf(s[t][2] - 4.0f), pv3 = __expf(s[t][3] - 4.0f);
                lsum += (pv0 + pv1) + (pv2 + pv3);
                pw.x = (_Float16)pv0; pw.y = (_Float16)pv1;
                pw.z = (_Float16)pv2; pw.w = (_Float16)pv3;
                *reinterpret_cast<half4*>(&Ps[rloc * 136 + 16*t + 4*quad]) = pw;
            }

            half8 pa[4];
            #pragma unroll
            for (int seg = 0; seg < 4; ++seg)
                pa[seg] = *reinterpret_cast<const half8*>(&Ps[rloc * 136 + seg * 32 + quad * 8]);
            __builtin_amdgcn_s_setprio(1);
            #pragma unroll
            for (int t = 0; t < 4; ++t) {
                #pragma unroll
                for (int seg = 0; seg < 4; ++seg) {
                    const int vp = ((4*seg + quad + colk) & 15) * 8;
                    const half8 vb = *reinterpret_cast<const half8*>(&Vs[cur][(16*t + colk) * 128 + vp]);
                    o[t] = mfma_f16(pa[seg], vb, o[t]);
                }
            }
            __builtin_amdgcn_s_setprio(0);

            __builtin_amdgcn_s_barrier();  // all waves done with bufs[cur]
            __builtin_amdgcn_sched_barrier(0);
            cur ^= 1;
        }

        lsum += __shfl_xor(lsum, 16, 64);
        lsum += __shfl_xor(lsum, 32, 64);

        float invr[4];
        #pragma unroll
        for (int r = 0; r < 4; ++r) invr[r] = 1.0f / __shfl(lsum, 4*quad + r, 64);
        #pragma unroll
        for (int t = 0; t < 4; ++t)
            #pragma unroll
            for (int r = 0; r < 4; ++r) {
                const int row = qt * 128 + wg * 64 + 16*wl + 4*quad + r;
                ((_Float16*)Ob)[(size_t)row * EMB + h * HDIM + 16*t + colk] =
                    (_Float16)(o[t][r] * invr[r]);
            }
    }
#undef STAGEKV
}

// =====================================================================
// Orchestration (5 dispatches). Workspace (64 MB) + d_out scratch:
//  ws: H16[0,8) Wk16[8,16) Wv16[16,24) FK[24,40) FV[40,56) Wo16[56,64)
//  d_out: Wq16[0,8) + Qbuf[8,16) — both dead before dispatch 5
//  dispatch 2 (gemm256 z=0..3): reads H16/Wk16/Wv16/Wq16/Wo/biases,
//    writes FK, FV, Qbuf (d_out[8,16)), Wo16 (ws[56,64)) — disjoint.
//  dispatch 3 (quant_kv): Kbuf[8,16) (Wk16 dead), Vt[16,24) (Wv16 dead)
//  dispatch 4 (flash): reads Qbuf/Kbuf/Vt, writes Obuf[24,32) (FK dead)
//  dispatch 5 (gemm O): reads Obuf + Wo16 (ws, untouched) + bo,
//    writes out = d_out[0,16) (Wq16/Qbuf dead).
// =====================================================================
extern "C" void kernel_launch(void* const* d_in, const int* in_sizes, int n_in,
                              void* d_out, int out_size, void* d_ws, size_t ws_size,
                              hipStream_t stream)
{
    const float* hidden = (const float*)d_in[0];
    const float* Wq = (const float*)d_in[1];
    const float* bq = (const float*)d_in[2];
    const float* Wk = (const float*)d_in[3];
    const float* bk = (const float*)d_in[4];
    const float* Wv = (const float*)d_in[5];
    const float* bv = (const float*)d_in[6];
    const float* Wo = (const float*)d_in[7];
    const float* bo = (const float*)d_in[8];
    float* out = (float*)d_out;

    char* ws = (char*)d_ws;
    const size_t MB = 1024 * 1024;
    u16*   H16  = (u16*)(ws);
    u16*   Wk16 = (u16*)(ws + 8 * MB);
    u16*   Wv16 = (u16*)(ws + 16 * MB);
    float* FK   = (float*)(ws + 24 * MB);
    float* FV   = (float*)(ws + 40 * MB);
    u16*   Wo16 = (u16*)(ws + 56 * MB);
    u16*   Kbuf = (u16*)(ws + 8 * MB);
    u16*   Vtb  = (u16*)(ws + 16 * MB);
    u16*   Obuf = (u16*)(ws + 24 * MB);          // over dead FK (after disp 3)
    u16*   Wq16 = (u16*)d_out;                   // d_out[0,8), dead after disp 2
    u16*   Qbuf = (u16*)((char*)d_out + 8 * MB); // d_out[8,16), dead after disp 4

    const dim3 cb(256);
    float* nilf = nullptr; u16* nil16 = nullptr;

    // 1. hidden/Wk/Wv/Wq -> fp16
    hipLaunchKernelGGL(cvt4, dim3(4096, 4), cb, 0, stream,
                       hidden, H16, Wk, Wk16, Wv, Wv16, Wq, Wq16);
    // 2. K/V/Q projections (z=0..2) + Wo convert on idle CUs (z=3)
    hipLaunchKernelGGL(gemm256, dim3(8, 8, 4), dim3(512), 0, stream,
                       H16, Wk16, Wv16, Wq16, bk, bv, bq,
                       Wo, Wo16, FK, FV, Qbuf);
    // 3. quantize K + V (V transposed)
    hipLaunchKernelGGL(quant_kv, dim3(1280), cb, 0, stream,
                       FK, Kbuf, FV, Vtb);
    // 4. attention: QBLK=128, 8-wave, double-buffered counted-vmcnt
    hipLaunchKernelGGL(flash128, dim3(256), dim3(512), 0, stream,
                       Qbuf, Kbuf, Vtb, Obuf);
    // 5. O projection, full-K single dispatch: out = Obuf @ Wo^T + bo
    hipLaunchKernelGGL(gemm16, dim3(16, 16, 1), cb, 0, stream,
                       Obuf, Wo16, nil16, nil16, bo, nilf, nilf,
                       out, nilf, nil16);
}

// Round 10
// 283.951 us; speedup vs baseline: 1.0564x; 1.0291x over previous
//
#include <hip/hip_runtime.h>
#include <math.h>

#define SEQ 2048
#define EMB 2048
#define NHEAD 32
#define HDIM 64

typedef unsigned short u16;
typedef _Float16 half8 __attribute__((ext_vector_type(8)));
typedef _Float16 half4 __attribute__((ext_vector_type(4)));
typedef __attribute__((ext_vector_type(4))) float floatx4;

__device__ __forceinline__ floatx4 mfma_f16(half8 a, half8 b, floatx4 c) {
    return __builtin_amdgcn_mfma_f32_16x16x32_f16(a, b, c, 0, 0, 0);
}
__device__ __forceinline__ void load16(const u16* g, u16* l) {
    __builtin_amdgcn_global_load_lds(
        (const __attribute__((address_space(1))) unsigned int*)g,
        (__attribute__((address_space(3))) unsigned int*)l, 16, 0, 0);
}
__device__ __forceinline__ u16 h2u(_Float16 h) { return *reinterpret_cast<u16*>(&h); }

// =====================================================================
// fp32 -> fp16 converter, 4 tensors of 4M elements (blockIdx.y).
// =====================================================================
__global__ __launch_bounds__(256)
void cvt4(const float* __restrict__ X0, u16* __restrict__ Y0,
          const float* __restrict__ X1, u16* __restrict__ Y1,
          const float* __restrict__ X2, u16* __restrict__ Y2,
          const float* __restrict__ X3, u16* __restrict__ Y3)
{
    const float* Xs[4] = {X0, X1, X2, X3};
    u16* Ys[4] = {Y0, Y1, Y2, Y3};
    const float* X = Xs[blockIdx.y];
    u16* Y = Ys[blockIdx.y];
    const int i = (blockIdx.x * 256 + threadIdx.x) * 4;
    float4 v = *reinterpret_cast<const float4*>(X + i);
    half4 hv;
    hv.x = (_Float16)v.x; hv.y = (_Float16)v.y;
    hv.z = (_Float16)v.z; hv.w = (_Float16)v.w;
    *reinterpret_cast<half4*>(Y + i) = hv;
}

// =====================================================================
// 256x256 fp16 MFMA GEMM (NT), 8-wave (2Mx4N), BK=64, double-buffered
// 128 KiB LDS, mod-8 oct swizzle folded into the DMA fetch address
// (0 bank conflicts).
//
// r10 change: 4-PHASE schedule (was 8). Each phase = one A-half x BOTH
// B-halves = 32 MFMA per barrier window (was 16); B-fragments persist
// across the phase pair. Barrier pairs 16 -> 8 per iteration, ds_reads
// 96 -> 48. Attacks the measured residual (MfmaUtil ~23%, nothing
// saturated -> per-window overhead dominates; r2/r3 changed reads/
// pipelining but never window count). Stage schedule re-derived race-
// free: PH1 stages buf1.Amq1+Bnq1<-k1 (last read prev PH3/PH4);
// PH2 stages buf0.Amq0+Bnq0<-k2 (read PH1), guard vmcnt(4) proves
// PH1's chunks landed before PH3 reads buf1; PH3 stages buf0.Amq1+
// Bnq1<-k2 (read PH2/PH1); PH4 stages buf1.Amq0+Bnq0<-k3 (read PH3),
// guard vmcnt(4) proves PH2/PH3's chunks landed before next PH1 reads
// buf0. Prologue: tile0 full + tile1 head (6 chunks), vmcnt(4). Tail
// wraps (&31) to dummy re-stages, final vmcnt(0) drains.
// Per-element accumulation order unchanged -> bitwise-identical output.
// z = blockIdx.z: 0 -> F0 = acc + bk; 1 -> F1 = acc + bv;
// 2 -> Qb = fp16((acc + bq) * 0.125); 3 -> Wo fp32->fp16 (64 blocks).
// =====================================================================
__global__ __launch_bounds__(512, 2)
void gemm256(const u16* __restrict__ A,
             const u16* __restrict__ B0, const u16* __restrict__ B1,
             const u16* __restrict__ B2,
             const float* __restrict__ bk, const float* __restrict__ bv,
             const float* __restrict__ bq,
             const float* __restrict__ Wo, u16* __restrict__ Wo16,
             float* __restrict__ F0, float* __restrict__ F1,
             u16* __restrict__ Qb)
{
    __shared__ __align__(16) u16 As[2][256 * 64];
    __shared__ __align__(16) u16 Bs[2][256 * 64];

    const int tid = threadIdx.x;
    const int bn = blockIdx.x, bm = blockIdx.y, z = blockIdx.z;

    if (z == 3) {        // Wo convert: 64 blocks x 512 threads x 128 elems
        const int b = bm * 8 + bn;
        #pragma unroll
        for (int c = 0; c < 32; ++c) {
            const int i = ((c * 64 + b) * 512 + tid) * 4;
            float4 v = *reinterpret_cast<const float4*>(Wo + i);
            half4 hv;
            hv.x = (_Float16)v.x; hv.y = (_Float16)v.y;
            hv.z = (_Float16)v.z; hv.w = (_Float16)v.w;
            *reinterpret_cast<half4*>(Wo16 + i) = hv;
        }
        return;
    }

    const int w = tid >> 6, lane = tid & 63;
    const int wm = w >> 2, wn = w & 3;          // 2 x 4 wave grid
    const int quad = lane >> 4, colk = lane & 15;
    const int lrow = lane >> 3, lphy = lane & 7;
    const int lsLog = (lphy - lrow) & 7;        // oct swizzle, pre-applied to src

    const u16* Bg  = (z == 0) ? B0 : (z == 1) ? B1 : B2;
    const u16* Ag  = A  + (size_t)(bm * 256 + lrow) * EMB + lsLog * 8;
    const u16* Bgp = Bg + (size_t)(bn * 256 + lrow) * EMB + lsLog * 8;

    const int kp0 = ((quad + colk) & 7) * 8;
    const int kp1 = ((quad + 4 + colk) & 7) * 8;
    int arow[8], brow[4];
    #pragma unroll
    for (int i = 0; i < 8; ++i) arow[i] = (wm * 128 + 16 * i + colk) * 64;
    #pragma unroll
    for (int j = 0; j < 4; ++j) brow[j] = (wn * 64 + 16 * j + colk) * 64;

    floatx4 acc[8][4];
    #pragma unroll
    for (int i = 0; i < 8; ++i)
        #pragma unroll
        for (int j = 0; j < 4; ++j) acc[i][j] = (floatx4){0.f, 0.f, 0.f, 0.f};

    half8 af[4][2], bf0[2][2], bf1[2][2];   // persistent fragments

#define STAGE_A(MQ, BUF, KT) {                                                \
    _Pragma("unroll") for (int p_ = 0; p_ < 2; ++p_) {                        \
        const int r0_ = 128 * p_ + (MQ) * 64 + w * 8;                         \
        load16(Ag + (size_t)r0_ * EMB + (KT), &As[BUF][r0_ * 64 + lane * 8]); \
    } }
#define STAGE_B(NQ, BUF, KT) {                                                \
    _Pragma("unroll") for (int p_ = 0; p_ < 2; ++p_) {                        \
        const int b_ = w + 8 * p_;                                            \
        const int r0_ = 64 * (b_ >> 2) + (NQ) * 32 + (b_ & 3) * 8;            \
        load16(Bgp + (size_t)r0_ * EMB + (KT), &Bs[BUF][r0_ * 64 + lane * 8]);\
    } }
#define READ_A(MQ, BUF)                                                       \
    _Pragma("unroll") for (int ii_ = 0; ii_ < 4; ++ii_) {                     \
        const u16* ap_ = &As[BUF][arow[4*(MQ)+ii_]];                          \
        af[ii_][0] = *reinterpret_cast<const half8*>(ap_ + kp0);              \
        af[ii_][1] = *reinterpret_cast<const half8*>(ap_ + kp1);              \
    }
#define READ_B2(BUF)                                                          \
    _Pragma("unroll") for (int jj_ = 0; jj_ < 2; ++jj_) {                     \
        const u16* b0_ = &Bs[BUF][brow[jj_]];                                 \
        bf0[jj_][0] = *reinterpret_cast<const half8*>(b0_ + kp0);             \
        bf0[jj_][1] = *reinterpret_cast<const half8*>(b0_ + kp1);             \
        const u16* b1_ = &Bs[BUF][brow[2+jj_]];                               \
        bf1[jj_][0] = *reinterpret_cast<const half8*>(b1_ + kp0);             \
        bf1[jj_][1] = *reinterpret_cast<const half8*>(b1_ + kp1);             \
    }

// One phase: A-half MQ x both B-halves (32 MFMA per barrier window).
#define PHASE2(MQ, RD, STG, GUARD) {                                          \
    RD                                                                        \
    STG                                                                       \
    __builtin_amdgcn_s_barrier();                                             \
    asm volatile("s_waitcnt lgkmcnt(0)" ::: "memory");                        \
    __builtin_amdgcn_s_setprio(1);                                            \
    _Pragma("unroll") for (int ii = 0; ii < 4; ++ii) {                        \
        _Pragma("unroll") for (int jj = 0; jj < 2; ++jj) {                    \
            acc[4*(MQ)+ii][jj] =                                              \
                mfma_f16(af[ii][0], bf0[jj][0], acc[4*(MQ)+ii][jj]);          \
            acc[4*(MQ)+ii][jj] =                                              \
                mfma_f16(af[ii][1], bf0[jj][1], acc[4*(MQ)+ii][jj]);          \
        }                                                                     \
        _Pragma("unroll") for (int jj = 0; jj < 2; ++jj) {                    \
            acc[4*(MQ)+ii][2+jj] =                                            \
                mfma_f16(af[ii][0], bf1[jj][0], acc[4*(MQ)+ii][2+jj]);        \
            acc[4*(MQ)+ii][2+jj] =                                            \
                mfma_f16(af[ii][1], bf1[jj][1], acc[4*(MQ)+ii][2+jj]);        \
        }                                                                     \
    }                                                                         \
    __builtin_amdgcn_s_setprio(0);                                            \
    if (GUARD) asm volatile("s_waitcnt vmcnt(4)" ::: "memory");               \
    __builtin_amdgcn_s_barrier();                                             \
    __builtin_amdgcn_sched_barrier(0);                                        \
}

    // Prologue: tile 0 complete (buf0) + tile 1 head (buf1.Amq0+Bnq0);
    // vmcnt(4) proves tile 0 landed (tile-1 head may stay in flight).
    STAGE_A(0, 0, 0)  STAGE_B(0, 0, 0)  STAGE_A(1, 0, 0)  STAGE_B(1, 0, 0)
    STAGE_A(0, 1, 64) STAGE_B(0, 1, 64)
    asm volatile("s_waitcnt vmcnt(4)" ::: "memory");
    __builtin_amdgcn_s_barrier();
    __builtin_amdgcn_sched_barrier(0);

    // Steady loop: iteration it consumes tiles 2it (buf0, PH1-PH2) and
    // 2it+1 (buf1, PH3-PH4); stages 2it+1 tail (PH1), 2it+2 (PH2-PH3),
    // 2it+3 head (PH4). Tail iterations wrap (&31) -> dummy re-stages
    // into already-consumed regions (harmless; final vmcnt(0) drains).
    #pragma unroll 1
    for (int it = 0; it < 16; ++it) {
        const int k1 = ((2 * it + 1) & 31) * 64;
        const int k2 = ((2 * it + 2) & 31) * 64;
        const int k3 = ((2 * it + 3) & 31) * 64;
        PHASE2(0, READ_A(0,0) READ_B2(0), STAGE_A(1,1,k1) STAGE_B(1,1,k1), 0)
        PHASE2(1, READ_A(1,0),            STAGE_A(0,0,k2) STAGE_B(0,0,k2), 1)
        PHASE2(0, READ_A(0,1) READ_B2(1), STAGE_A(1,0,k2) STAGE_B(1,0,k2), 0)
        PHASE2(1, READ_A(1,1),            STAGE_A(0,1,k3) STAGE_B(0,1,k3), 1)
    }
    asm volatile("s_waitcnt vmcnt(0)" ::: "memory");  // drain before endpgm

#undef STAGE_A
#undef STAGE_B
#undef READ_A
#undef READ_B2
#undef PHASE2

    const float* bias = (z == 0) ? bk : (z == 1) ? bv : bq;
    #pragma unroll
    for (int i = 0; i < 8; ++i) {
        const int row = bm * 256 + wm * 128 + 16 * i + 4 * quad;
        #pragma unroll
        for (int j = 0; j < 4; ++j) {
            const int col = bn * 256 + wn * 64 + 16 * j + colk;
            const float bb = bias[col];
            #pragma unroll
            for (int r = 0; r < 4; ++r) {
                const size_t idx = (size_t)(row + r) * EMB + col;
                if (z == 2)
                    ((_Float16*)Qb)[idx] = (_Float16)((acc[i][j][r] + bb) * 0.125f);
                else
                    ((z == 0) ? F0 : F1)[idx] = acc[i][j][r] + bb;
            }
        }
    }
}

// =====================================================================
// 128x128 fp16 MFMA GEMM (NT), BK=64: kept for the O-projection
// (2048^2 output -> 256 blocks = full CU coverage).
// =====================================================================
__global__ __launch_bounds__(256)
void gemm16(const u16* __restrict__ A,
            const u16* __restrict__ B0, const u16* __restrict__ B1,
            const u16* __restrict__ B2,
            const float* __restrict__ bk, const float* __restrict__ bv,
            const float* __restrict__ bq,
            float* __restrict__ F0, float* __restrict__ F1,
            u16* __restrict__ Qb)
{
    __shared__ __align__(16) u16 As[128 * 64];
    __shared__ __align__(16) u16 Bs[128 * 64];

    const int tid = threadIdx.x;
    const int w = tid >> 6, lane = tid & 63;
    const int quad = lane >> 4, colk = lane & 15;
    const int bn = blockIdx.x, bm = blockIdx.y, z = blockIdx.z;
    const int wm = (w & 1) * 64, wn = (w >> 1) * 64;

    const u16* Bg = (z == 0) ? B0 : (z == 1) ? B1 : B2;

    const int srow = tid >> 3, sphy = tid & 7;
    const int sLog = (sphy - srow) & 7;
    size_t agof[4], bgof[4];
    int ldst[4];
    #pragma unroll
    for (int p = 0; p < 4; ++p) {
        const int row = srow + 32 * p;
        agof[p] = (size_t)(bm * 128 + row) * EMB + sLog * 8;
        bgof[p] = (size_t)(bn * 128 + row) * EMB + sLog * 8;
        ldst[p] = (tid + 256 * p) * 8;
    }

    const int aoct0 = ((quad + colk) & 7) * 8;
    const int aoct1 = ((quad + 4 + colk) & 7) * 8;

    floatx4 acc[4][4];
    #pragma unroll
    for (int i = 0; i < 4; ++i)
        #pragma unroll
        for (int j = 0; j < 4; ++j) acc[i][j] = (floatx4){0.f, 0.f, 0.f, 0.f};

    for (int kt = 0; kt < 2048; kt += 64) {
        __syncthreads();
        #pragma unroll
        for (int p = 0; p < 4; ++p) {
            load16(A  + agof[p] + kt, As + ldst[p]);
            load16(Bg + bgof[p] + kt, Bs + ldst[p]);
        }
        __syncthreads();

        half8 a0[4], a1[4], b0[4], b1[4];
        #pragma unroll
        for (int i = 0; i < 4; ++i) {
            a0[i] = *reinterpret_cast<const half8*>(&As[(wm + 16*i + colk) * 64 + aoct0]);
            a1[i] = *reinterpret_cast<const half8*>(&As[(wm + 16*i + colk) * 64 + aoct1]);
        }
        #pragma unroll
        for (int j = 0; j < 4; ++j) {
            b0[j] = *reinterpret_cast<const half8*>(&Bs[(wn + 16*j + colk) * 64 + aoct0]);
            b1[j] = *reinterpret_cast<const half8*>(&Bs[(wn + 16*j + colk) * 64 + aoct1]);
        }
        #pragma unroll
        for (int i = 0; i < 4; ++i)
            #pragma unroll
            for (int j = 0; j < 4; ++j) {
                acc[i][j] = mfma_f16(a0[i], b0[j], acc[i][j]);
                acc[i][j] = mfma_f16(a1[i], b1[j], acc[i][j]);
            }
    }

    const float* bias = (z == 0) ? bk : (z == 1) ? bv : bq;
    #pragma unroll
    for (int i = 0; i < 4; ++i) {
        const int row = bm * 128 + wm + 16*i + 4*quad;
        #pragma unroll
        for (int j = 0; j < 4; ++j) {
            const int col = bn * 128 + wn + 16*j + colk;
            const float bv2 = bias[col];
            #pragma unroll
            for (int r = 0; r < 4; ++r) {
                const size_t idx = (size_t)(row + r) * EMB + col;
                if (z == 2)
                    ((_Float16*)Qb)[idx] = (_Float16)((acc[i][j][r] + bv2) * 0.125f);
                else
                    ((z == 0) ? F0 : F1)[idx] = acc[i][j][r] + bv2;
            }
        }
    }
}

// =====================================================================
// QuotRem fake-quantize core (q_bits=1, r_bits=3, gs=16), exact ref
// semantics on fp32 pre-quant values.
// =====================================================================
__device__ __forceinline__ void quotrem16(float* x)
{
    float maxabs = 1e-8f, maxpos = -INFINITY, minval = INFINITY;
    #pragma unroll
    for (int i = 0; i < 16; ++i) {
        maxabs = fmaxf(maxabs, fabsf(x[i]));
        maxpos = fmaxf(maxpos, x[i]);
        minval = fminf(minval, x[i]);
    }
    const float lg = log2f(maxabs);
    const float bfl = exp2f(floorf(lg));
    const float bcl = exp2f(ceilf(lg));
    float base = (fabsf(maxabs - bfl) <= fabsf(bcl - maxabs)) ? bfl : bcl;
    base = fminf(fmaxf(base, 1.0f), 128.0f);
    const float sgn = (fabsf(maxpos) >= fabsf(minval)) ? 1.0f : -1.0f;
    const float hb = 0.5f * base, sb = sgn * base;

    float qs[16], r[16], maxr = 1e-8f;
    #pragma unroll
    for (int i = 0; i < 16; ++i) {
        qs[i] = (x[i] * sgn >= hb) ? sb : 0.0f;
        r[i]  = x[i] - qs[i];
        maxr  = fmaxf(maxr, fabsf(r[i]));
    }
    const float scale = maxr / 3.0f;
    #pragma unroll
    for (int i = 0; i < 16; ++i) {
        float rq = rintf(r[i] / scale);
        rq = fminf(fmaxf(rq, -4.0f), 3.0f);
        x[i] = qs[i] + rq * scale;
    }
}

// =====================================================================
// quant_kv: bid < 1024 -> K quant (packed half8 stores);
// bid >= 1024 -> V quant + per-head transpose via LDS tile.
// =====================================================================
__global__ __launch_bounds__(256)
void quant_kv(const float* __restrict__ FK, u16* __restrict__ Kb,
              const float* __restrict__ FV, u16* __restrict__ Vt)
{
    __shared__ u16 T[64 * 264];
    const int bid = blockIdx.x, t = threadIdx.x;

    if (bid < 1024) {    // K path
        const int g = bid * 256 + t;
        const float* p = FK + (size_t)g * 16;
        float x[16];
        #pragma unroll
        for (int i = 0; i < 16; i += 4)
            *reinterpret_cast<float4*>(&x[i]) = *reinterpret_cast<const float4*>(p + i);
        quotrem16(x);
        half8 h0, h1;
        #pragma unroll
        for (int i = 0; i < 8; ++i) {
            h0[i] = (_Float16)x[i];
            h1[i] = (_Float16)x[8 + i];
        }
        u16* o = Kb + (size_t)g * 16;
        *reinterpret_cast<half8*>(o) = h0;
        *reinterpret_cast<half8*>(o + 8) = h1;
        return;
    }

    const int l = bid - 1024;   // V path: 256 blocks
    const int sb = l >> 5, h = l & 31;
    const float* src = FV + (size_t)(sb * 256 + t) * EMB + h * HDIM;

    #pragma unroll
    for (int g4 = 0; g4 < 4; ++g4) {
        float x[16];
        #pragma unroll
        for (int i = 0; i < 16; i += 4)
            *reinterpret_cast<float4*>(&x[i]) =
                *reinterpret_cast<const float4*>(src + g4 * 16 + i);
        quotrem16(x);
        #pragma unroll
        for (int i = 0; i < 16; ++i)
            T[(g4 * 16 + i) * 264 + t] = h2u((_Float16)x[i]);
    }
    __syncthreads();

    const int d = t >> 2, seg = t & 3;
    u16* dst = Vt + (size_t)(h * HDIM + d) * SEQ + sb * 256 + seg * 64;
    #pragma unroll
    for (int jj = 0; jj < 8; ++jj)
        *reinterpret_cast<half8*>(dst + jj * 8) =
            *reinterpret_cast<const half8*>(&T[d * 264 + seg * 64 + jj * 8]);
}

// =====================================================================
// Causal flash attention, fp16 MFMA, S^T formulation, BC=128 windows,
// fixed-shift softmax (P = exp(s-4)). QBLK=128, 512 threads (8 waves),
// double-buffered K/V with counted vmcnt, setprio around MFMA clusters
// (r7 configuration — best measured). Grid: 256 paired blocks
// (uniform 17 windows), XCD-clustered.
// =====================================================================
__global__ __launch_bounds__(512)
void flash128(const u16* __restrict__ Qb, const u16* __restrict__ Kb,
              const u16* __restrict__ Vt, u16* __restrict__ Ob)
{
    __shared__ __align__(16) u16 Ks[2][128 * 64];   // [key][d], swizzled octs
    __shared__ __align__(16) u16 Vs[2][64 * 128];   // [d][key], swizzled octs
    __shared__ __align__(16) u16 Ps[128 * 136];     // P[q][key], wave-local rows

    const int tid = threadIdx.x;
    const int w = tid >> 6, lane = tid & 63;
    const int wg = w >> 2, wl = w & 3;            // row-half group, wave-in-group
    const int quad = lane >> 4, colk = lane & 15;
    const int id = blockIdx.x;                    // 0..255
    const int h = (id & 7) * 4 + ((id >> 3) & 3); // head, XCD-clustered
    const int pairb = id >> 5;                    // 0..7

    int krow[2], koff[2], vd[2], voff[2], ldst[2];
    #pragma unroll
    for (int p = 0; p < 2; ++p) {
        const int c = tid + p * 512;
        krow[p] = c >> 3;
        koff[p] = (((c & 7) - krow[p]) & 7) * 8;
        vd[p]   = c >> 4;
        voff[p] = (((c & 15) - vd[p]) & 15) * 8;
        ldst[p] = c * 8;
    }
    const int kp0 = ((quad + colk) & 7) * 8;
    const int kp1 = ((quad + 4 + colk) & 7) * 8;
    const int rloc = wg * 64 + 16 * wl + colk;    // lane's q-row within block

#define STAGEKV(KW, BUF) {                                                     \
    _Pragma("unroll") for (int p_ = 0; p_ < 2; ++p_) {                         \
        load16(Kb + (size_t)((KW) * 128 + krow[p_]) * EMB + h * HDIM + koff[p_],\
               &Ks[BUF][ldst[p_]]);                                            \
        load16(Vt + (size_t)(h * HDIM + vd[p_]) * SEQ + (KW) * 128 + voff[p_], \
               &Vs[BUF][ldst[p_]]);                                            \
    } }

    #pragma unroll
    for (int pass = 0; pass < 2; ++pass) {
        const int qt = pass ? (15 - pairb) : pairb;
        const int nw = qt + 1;
        const int qrow_g = qt * 128 + rloc;

        const half8 qb0 = *reinterpret_cast<const half8*>(
            &Qb[(size_t)qrow_g * EMB + h * HDIM + quad * 8]);
        const half8 qb1 = *reinterpret_cast<const half8*>(
            &Qb[(size_t)qrow_g * EMB + h * HDIM + 32 + quad * 8]);

        STAGEKV(0, 0)                      // window 0 -> buf 0

        floatx4 o[4];
        #pragma unroll
        for (int t = 0; t < 4; ++t) o[t] = (floatx4){0.f, 0.f, 0.f, 0.f};
        float lsum = 0.f;
        int cur = 0;

        #pragma unroll 1
        for (int kw = 0; kw < nw; ++kw) {
            if (kw + 1 < nw) {
                STAGEKV(kw + 1, cur ^ 1)   // 4 loads in flight across compute
                asm volatile("s_waitcnt vmcnt(4)" ::: "memory");
            } else {
                asm volatile("s_waitcnt vmcnt(0)" ::: "memory");
            }
            __builtin_amdgcn_s_barrier();  // all waves' window-kw data landed
            __builtin_amdgcn_sched_barrier(0);

            floatx4 s[8];
            __builtin_amdgcn_s_setprio(1);
            #pragma unroll
            for (int t = 0; t < 8; ++t) {
                const half8 kb0 = *reinterpret_cast<const half8*>(&Ks[cur][(16*t + colk) * 64 + kp0]);
                const half8 kb1 = *reinterpret_cast<const half8*>(&Ks[cur][(16*t + colk) * 64 + kp1]);
                floatx4 zz = (floatx4){0.f, 0.f, 0.f, 0.f};
                zz = mfma_f16(kb0, qb0, zz);
                s[t] = mfma_f16(kb1, qb1, zz);
            }
            __builtin_amdgcn_s_setprio(0);
            if (kw == nw - 1) {
                #pragma unroll
                for (int t = 0; t < 8; ++t)
                    #pragma unroll
                    for (int r = 0; r < 4; ++r)
                        if (kw * 128 + 16*t + 4*quad + r > qrow_g) s[t][r] = -INFINITY;
            }

            #pragma unroll
            for (int t = 0; t < 8; ++t) {
                half4 pw;
                float pv0 = __expf(s[t][0] - 4.0f), pv1 = __expf(s[t][1] - 4.0f);
                float pv2 = __expf(s[t][2] - 4.0f), pv3 = __expf(s[t][3] - 4.0f);
                lsum += (pv0 + pv1) + (pv2 + pv3);
                pw.x = (_Float16)pv0; pw.y = (_Float16)pv1;
                pw.z = (_Float16)pv2; pw.w = (_Float16)pv3;
                *reinterpret_cast<half4*>(&Ps[rloc * 136 + 16*t + 4*quad]) = pw;
            }

            half8 pa[4];
            #pragma unroll
            for (int seg = 0; seg < 4; ++seg)
                pa[seg] = *reinterpret_cast<const half8*>(&Ps[rloc * 136 + seg * 32 + quad * 8]);
            __builtin_amdgcn_s_setprio(1);
            #pragma unroll
            for (int t = 0; t < 4; ++t) {
                #pragma unroll
                for (int seg = 0; seg < 4; ++seg) {
                    const int vp = ((4*seg + quad + colk) & 15) * 8;
                    const half8 vb = *reinterpret_cast<const half8*>(&Vs[cur][(16*t + colk) * 128 + vp]);
                    o[t] = mfma_f16(pa[seg], vb, o[t]);
                }
            }
            __builtin_amdgcn_s_setprio(0);

            __builtin_amdgcn_s_barrier();  // all waves done with bufs[cur]
            __builtin_amdgcn_sched_barrier(0);
            cur ^= 1;
        }

        lsum += __shfl_xor(lsum, 16, 64);
        lsum += __shfl_xor(lsum, 32, 64);

        float invr[4];
        #pragma unroll
        for (int r = 0; r < 4; ++r) invr[r] = 1.0f / __shfl(lsum, 4*quad + r, 64);
        #pragma unroll
        for (int t = 0; t < 4; ++t)
            #pragma unroll
            for (int r = 0; r < 4; ++r) {
                const int row = qt * 128 + wg * 64 + 16*wl + 4*quad + r;
                ((_Float16*)Ob)[(size_t)row * EMB + h * HDIM + 16*t + colk] =
                    (_Float16)(o[t][r] * invr[r]);
            }
    }
#undef STAGEKV
}

// =====================================================================
// Orchestration (5 dispatches). Workspace (64 MB) + d_out scratch:
//  ws: H16[0,8) Wk16[8,16) Wv16[16,24) FK[24,40) FV[40,56) Wo16[56,64)
//  d_out: Wq16[0,8) + Qbuf[8,16) — both dead before dispatch 5
//  dispatch 2 (gemm256 z=0..3): reads H16/Wk16/Wv16/Wq16/Wo/biases,
//    writes FK, FV, Qbuf (d_out[8,16)), Wo16 (ws[56,64)) — disjoint.
//  dispatch 3 (quant_kv): Kbuf[8,16) (Wk16 dead), Vt[16,24) (Wv16 dead)
//  dispatch 4 (flash): reads Qbuf/Kbuf/Vt, writes Obuf[24,32) (FK dead)
//  dispatch 5 (gemm O): reads Obuf + Wo16 + bo, writes out (d_out).
// =====================================================================
extern "C" void kernel_launch(void* const* d_in, const int* in_sizes, int n_in,
                              void* d_out, int out_size, void* d_ws, size_t ws_size,
                              hipStream_t stream)
{
    const float* hidden = (const float*)d_in[0];
    const float* Wq = (const float*)d_in[1];
    const float* bq = (const float*)d_in[2];
    const float* Wk = (const float*)d_in[3];
    const float* bk = (const float*)d_in[4];
    const float* Wv = (const float*)d_in[5];
    const float* bv = (const float*)d_in[6];
    const float* Wo = (const float*)d_in[7];
    const float* bo = (const float*)d_in[8];
    float* out = (float*)d_out;

    char* ws = (char*)d_ws;
    const size_t MB = 1024 * 1024;
    u16*   H16  = (u16*)(ws);
    u16*   Wk16 = (u16*)(ws + 8 * MB);
    u16*   Wv16 = (u16*)(ws + 16 * MB);
    float* FK   = (float*)(ws + 24 * MB);
    float* FV   = (float*)(ws + 40 * MB);
    u16*   Wo16 = (u16*)(ws + 56 * MB);
    u16*   Kbuf = (u16*)(ws + 8 * MB);
    u16*   Vtb  = (u16*)(ws + 16 * MB);
    u16*   Obuf = (u16*)(ws + 24 * MB);          // over dead FK (after disp 3)
    u16*   Wq16 = (u16*)d_out;                   // d_out[0,8), dead after disp 2
    u16*   Qbuf = (u16*)((char*)d_out + 8 * MB); // d_out[8,16), dead after disp 4

    const dim3 cb(256);
    float* nilf = nullptr; u16* nil16 = nullptr;

    // 1. hidden/Wk/Wv/Wq -> fp16
    hipLaunchKernelGGL(cvt4, dim3(4096, 4), cb, 0, stream,
                       hidden, H16, Wk, Wk16, Wv, Wv16, Wq, Wq16);
    // 2. K/V/Q projections (4-phase schedule) + Wo convert (z=3)
    hipLaunchKernelGGL(gemm256, dim3(8, 8, 4), dim3(512), 0, stream,
                       H16, Wk16, Wv16, Wq16, bk, bv, bq,
                       Wo, Wo16, FK, FV, Qbuf);
    // 3. quantize K + V (V transposed)
    hipLaunchKernelGGL(quant_kv, dim3(1280), cb, 0, stream,
                       FK, Kbuf, FV, Vtb);
    // 4. attention: QBLK=128, 8-wave, double-buffered counted-vmcnt
    hipLaunchKernelGGL(flash128, dim3(256), dim3(512), 0, stream,
                       Qbuf, Kbuf, Vtb, Obuf);
    // 5. O projection, full-K single dispatch: out = Obuf @ Wo^T + bo
    hipLaunchKernelGGL(gemm16, dim3(16, 16, 1), cb, 0, stream,
                       Obuf, Wo16, nil16, nil16, bo, nilf, nilf,
                       out, nilf, nil16);
}